// Round 1
// baseline (207.136 us; speedup 1.0000x reference)
//
#include <hip/hip_runtime.h>
#include <math.h>

typedef __attribute__((ext_vector_type(8))) short short8;
typedef __attribute__((ext_vector_type(4))) float floatx4;

#define HPAD 264  // bf16 elements per LDS h-row: 256 + 8 pad (row stride 528 B, 16B aligned)

__device__ __forceinline__ unsigned short f2bf(float x) {
    union { float f; unsigned int u; } v; v.f = x;
    unsigned int u = v.u;
    return (unsigned short)((u + 0x7fffu + ((u >> 16) & 1u)) >> 16);  // RNE
}

// Exact-GELU via branchless A&S 7.1.26 erf (max |err| 1.5e-7 — below fp32 noise
// for this use, and far below the bf16 quantization already applied to h).
// ~16 VALU ops, no divergence, vs libm erff's divergent two-path ~100+ cyc.
__device__ __forceinline__ float gelu_erf(float x) {
    float z  = x * 0.70710678118654752f;
    float az = fabsf(z);
    float t  = __builtin_amdgcn_rcpf(fmaf(0.3275911f, az, 1.0f));
    float p  = fmaf(t, 1.061405429f, -1.453152027f);
    p = fmaf(t, p, 1.421413741f);
    p = fmaf(t, p, -0.284496736f);
    p = fmaf(t, p, 0.254829592f);
    p = p * t;
    float e  = __expf(-z * z);        // v_exp_f32 path, underflows cleanly for large |z|
    float er = fmaf(-p, e, 1.0f);     // erf(|z|)
    er = copysignf(er, z);
    return 0.5f * x * (1.0f + er);
}

// ---------------------------------------------------------------------------
// Prep kernel: blocks [0,256) compute F1 = feat @ W1[4:,:]  (no bias)
//              blocks [256,288) pack W2 (fp32 row-major 256x256) into bf16
//              MFMA B-fragment order: pk[(kt*16+nt)*64 + lane][e] =
//              bf16(W2[(kt*32 + (lane>>4)*8 + e)*256 + nt*16 + (lane&15)])
// ---------------------------------------------------------------------------
__global__ __launch_bounds__(256) void prep_kernel(
    const float* __restrict__ feat,   // [32,64,256]
    const float* __restrict__ W1,     // [260,256]
    const float* __restrict__ W2,     // [256,256]
    float* __restrict__ F1,           // ws: [2048,256]
    unsigned short* __restrict__ pk)  // ws: [65536] bf16
{
    int tid = threadIdx.x;
    if (blockIdx.x < 256) {
        __shared__ float sh[8][256];
        int b  = blockIdx.x >> 3;
        int r0 = (blockIdx.x & 7) * 8;
        const float* fb = feat + (size_t)(b * 64 + r0) * 256;
        #pragma unroll
        for (int r = 0; r < 8; r++) sh[r][tid] = fb[r * 256 + tid];
        __syncthreads();
        float acc[8] = {0.f, 0.f, 0.f, 0.f, 0.f, 0.f, 0.f, 0.f};
        const float* w = W1 + 4 * 256 + tid;
        #pragma unroll 4
        for (int c = 0; c < 256; c++) {
            float wv = w[(size_t)c * 256];
            #pragma unroll
            for (int r = 0; r < 8; r++) acc[r] += sh[r][c] * wv;
        }
        float* o = F1 + (size_t)(b * 64 + r0) * 256 + tid;
        #pragma unroll
        for (int r = 0; r < 8; r++) o[r * 256] = acc[r];
    } else {
        int g = (blockIdx.x - 256) * 256 + tid;   // 0..8191
        int kt   = g >> 10;
        int rem  = g & 1023;
        int nt   = rem >> 6;
        int lane = rem & 63;
        int n  = nt * 16 + (lane & 15);
        int kb = kt * 32 + (lane >> 4) * 8;
        short8 v;
        #pragma unroll
        for (int e = 0; e < 8; e++) v[e] = (short)f2bf(W2[(size_t)(kb + e) * 256 + n]);
        ((short8*)pk)[g] = v;
    }
}

// ---------------------------------------------------------------------------
// Main kernel: one block per (b, i). 256 threads = 4 waves.
// Phase 1: geo[j] (64 entries) -> LDS
// Phase 2: h[j][d] = gelu(F1[i,d]-F1[j,d] + geo.W1geo + b1[d]) -> bf16 LDS
//          (4 d per thread, 16 j per thread; float4 loads, ds_write_b64)
// Phase 3: out[b,i,j,:] = h[64x256] @ W2[256x256] + b2, via 16x16x32 bf16 MFMA
// ---------------------------------------------------------------------------
__global__ __launch_bounds__(256) void edge_kernel(
    const float* __restrict__ F1,     // [2048,256]
    const float* __restrict__ pos,    // [32,64,2]
    const float* __restrict__ W1,     // [260,256] (rows 0..3 = geo)
    const float* __restrict__ b1,     // [256]
    const unsigned short* __restrict__ pkW2, // packed bf16 W2
    const float* __restrict__ b2,     // [256]
    float* __restrict__ out)          // [32,64,64,256]
{
    __shared__ unsigned short hsh[64 * HPAD];  // 33792 B
    __shared__ float geo[64][4];               // 1024 B

    int bx  = blockIdx.x;
    int b   = bx >> 6;
    int i   = bx & 63;
    int tid = threadIdx.x;

    // ---- phase 1: geometry per j ----
    if (tid < 64) {
        float xi = pos[(b * 64 + i)   * 2 + 0], yi = pos[(b * 64 + i)   * 2 + 1];
        float xj = pos[(b * 64 + tid) * 2 + 0], yj = pos[(b * 64 + tid) * 2 + 1];
        float dx = xi - xj, dy = yi - yj;
        float dist = sqrtf(dx * dx + dy * dy);
        float ang  = atan2f(dy, dx);
        geo[tid][0] = dx; geo[tid][1] = dy; geo[tid][2] = dist; geo[tid][3] = ang;
    }
    __syncthreads();

    // ---- phase 2: h tile (each thread: 4 consecutive d, 16 j values) ----
    {
        int qd = tid & 63;            // d quad index (d0 = qd*4)
        int jg = tid >> 6;            // j residue (j = jj*4 + jg)
        const float4* F1b4 = (const float4*)(F1 + (size_t)b * 64 * 256);
        float4 fi = F1b4[i * 64 + qd];
        float4 w0 = ((const float4*)(W1 + 0 * 256))[qd];
        float4 w1 = ((const float4*)(W1 + 1 * 256))[qd];
        float4 w2 = ((const float4*)(W1 + 2 * 256))[qd];
        float4 w3 = ((const float4*)(W1 + 3 * 256))[qd];
        float4 bb = ((const float4*)b1)[qd];
        float bx0 = fi.x + bb.x, bx1 = fi.y + bb.y;
        float bx2 = fi.z + bb.z, bx3 = fi.w + bb.w;
        int d0 = qd * 4;
        #pragma unroll 4
        for (int jj = 0; jj < 16; jj++) {
            int j = jj * 4 + jg;
            float4 g  = *(const float4*)&geo[j][0];
            float4 fj = F1b4[j * 64 + qd];
            float x0 = fmaf(g.x, w0.x, fmaf(g.y, w1.x, fmaf(g.z, w2.x, fmaf(g.w, w3.x, bx0 - fj.x))));
            float x1 = fmaf(g.x, w0.y, fmaf(g.y, w1.y, fmaf(g.z, w2.y, fmaf(g.w, w3.y, bx1 - fj.y))));
            float x2 = fmaf(g.x, w0.z, fmaf(g.y, w1.z, fmaf(g.z, w2.z, fmaf(g.w, w3.z, bx2 - fj.z))));
            float x3 = fmaf(g.x, w0.w, fmaf(g.y, w1.w, fmaf(g.z, w2.w, fmaf(g.w, w3.w, bx3 - fj.w))));
            float g0 = gelu_erf(x0);
            float g1 = gelu_erf(x1);
            float g2 = gelu_erf(x2);
            float g3 = gelu_erf(x3);
            uint2 pv;
            pv.x = (unsigned int)f2bf(g0) | ((unsigned int)f2bf(g1) << 16);
            pv.y = (unsigned int)f2bf(g2) | ((unsigned int)f2bf(g3) << 16);
            *(uint2*)&hsh[j * HPAD + d0] = pv;   // 8B store, bank-minimal
        }
    }
    __syncthreads();

    // ---- phase 3: GEMM h[64x256] @ W2[256x256] ----
    int w    = tid >> 6;          // wave id: owns cols [w*64, w*64+64)
    int lane = tid & 63;
    int q    = lane >> 4;
    int m16  = lane & 15;

    floatx4 acc[4][4];
    #pragma unroll
    for (int a = 0; a < 4; a++)
        #pragma unroll
        for (int c = 0; c < 4; c++) acc[a][c] = (floatx4){0.f, 0.f, 0.f, 0.f};

    const short8* pk = (const short8*)pkW2;
    #pragma unroll
    for (int ks = 0; ks < 8; ks++) {
        short8 afr[4];
        #pragma unroll
        for (int mt = 0; mt < 4; mt++) {
            int row = mt * 16 + m16;
            afr[mt] = *(const short8*)&hsh[row * HPAD + ks * 32 + q * 8];
        }
        short8 bfr[4];
        #pragma unroll
        for (int nt = 0; nt < 4; nt++)
            bfr[nt] = pk[(ks * 16 + (w * 4 + nt)) * 64 + lane];
        __builtin_amdgcn_s_setprio(1);
        #pragma unroll
        for (int mt = 0; mt < 4; mt++)
            #pragma unroll
            for (int nt = 0; nt < 4; nt++)
                acc[mt][nt] = __builtin_amdgcn_mfma_f32_16x16x32_bf16(
                    afr[mt], bfr[nt], acc[mt][nt], 0, 0, 0);
        __builtin_amdgcn_s_setprio(0);
    }

    // ---- epilogue: D[row=(q*4+r)+mt*16][col=m16+nt*16+w*64] + b2 ----
    float* ob = out + (size_t)bx * 64 * 256;
    #pragma unroll
    for (int nt = 0; nt < 4; nt++) {
        int col = w * 64 + nt * 16 + m16;
        float bias = b2[col];
        #pragma unroll
        for (int mt = 0; mt < 4; mt++) {
            int rbase = mt * 16 + q * 4;
            #pragma unroll
            for (int r = 0; r < 4; r++)
                ob[(size_t)(rbase + r) * 256 + col] = acc[mt][nt][r] + bias;
        }
    }
}

extern "C" void kernel_launch(void* const* d_in, const int* in_sizes, int n_in,
                              void* d_out, int out_size, void* d_ws, size_t ws_size,
                              hipStream_t stream) {
    const float* feat = (const float*)d_in[0];  // [32,64,256]
    const float* pos  = (const float*)d_in[1];  // [32,64,2]
    const float* W1   = (const float*)d_in[2];  // [260,256]
    const float* b1   = (const float*)d_in[3];  // [256]
    const float* W2   = (const float*)d_in[4];  // [256,256]
    const float* b2   = (const float*)d_in[5];  // [256]
    float* out = (float*)d_out;

    float* F1 = (float*)d_ws;                          // 2048*256*4 = 2 MiB
    unsigned short* pk = (unsigned short*)((char*)d_ws + 2048 * 256 * 4); // 128 KiB

    prep_kernel<<<288, 256, 0, stream>>>(feat, W1, W2, F1, pk);
    edge_kernel<<<2048, 256, 0, stream>>>(F1, pos, W1, b1, pk, b2, out);
}

// Round 2
// 193.483 us; speedup vs baseline: 1.0706x; 1.0706x over previous
//
#include <hip/hip_runtime.h>
#include <math.h>

typedef __attribute__((ext_vector_type(8))) short short8;
typedef __attribute__((ext_vector_type(4))) float floatx4;

#define HPAD 264  // bf16 elements per LDS h-row: 256 + 8 pad (row stride 528 B, 16B aligned)

__device__ __forceinline__ unsigned short f2bf(float x) {
    union { float f; unsigned int u; } v; v.f = x;
    unsigned int u = v.u;
    return (unsigned short)((u + 0x7fffu + ((u >> 16) & 1u)) >> 16);  // RNE
}

// Exact-GELU via branchless A&S 7.1.26 erf (max |err| 1.5e-7).
__device__ __forceinline__ float gelu_erf(float x) {
    float z  = x * 0.70710678118654752f;
    float az = fabsf(z);
    float t  = __builtin_amdgcn_rcpf(fmaf(0.3275911f, az, 1.0f));
    float p  = fmaf(t, 1.061405429f, -1.453152027f);
    p = fmaf(t, p, 1.421413741f);
    p = fmaf(t, p, -0.284496736f);
    p = fmaf(t, p, 0.254829592f);
    p = p * t;
    float e  = __expf(-z * z);
    float er = fmaf(-p, e, 1.0f);
    er = copysignf(er, z);
    return 0.5f * x * (1.0f + er);
}

// ---------------------------------------------------------------------------
// Prep kernel: blocks [0,256) compute F1 = feat @ W1[4:,:]  (no bias)
//              blocks [256,288) pack W2 into bf16 MFMA B-fragment order.
// ---------------------------------------------------------------------------
__global__ __launch_bounds__(256) void prep_kernel(
    const float* __restrict__ feat,   // [32,64,256]
    const float* __restrict__ W1,     // [260,256]
    const float* __restrict__ W2,     // [256,256]
    float* __restrict__ F1,           // ws: [2048,256]
    unsigned short* __restrict__ pk)  // ws: [65536] bf16
{
    int tid = threadIdx.x;
    if (blockIdx.x < 256) {
        __shared__ float sh[8][256];
        int b  = blockIdx.x >> 3;
        int r0 = (blockIdx.x & 7) * 8;
        const float* fb = feat + (size_t)(b * 64 + r0) * 256;
        #pragma unroll
        for (int r = 0; r < 8; r++) sh[r][tid] = fb[r * 256 + tid];
        __syncthreads();
        float acc[8] = {0.f, 0.f, 0.f, 0.f, 0.f, 0.f, 0.f, 0.f};
        const float* w = W1 + 4 * 256 + tid;
        #pragma unroll 8
        for (int c = 0; c < 256; c++) {
            float wv = w[(size_t)c * 256];
            #pragma unroll
            for (int r = 0; r < 8; r++) acc[r] += sh[r][c] * wv;
        }
        float* o = F1 + (size_t)(b * 64 + r0) * 256 + tid;
        #pragma unroll
        for (int r = 0; r < 8; r++) o[r * 256] = acc[r];
    } else {
        int g = (blockIdx.x - 256) * 256 + tid;   // 0..8191
        int kt   = g >> 10;
        int rem  = g & 1023;
        int nt   = rem >> 6;
        int lane = rem & 63;
        int n  = nt * 16 + (lane & 15);
        int kb = kt * 32 + (lane >> 4) * 8;
        short8 v;
        #pragma unroll
        for (int e = 0; e < 8; e++) v[e] = (short)f2bf(W2[(size_t)(kb + e) * 256 + n]);
        ((short8*)pk)[g] = v;
    }
}

// ---------------------------------------------------------------------------
// Main kernel: one block per (b, i). 256 threads = 4 waves.
// Phase 1: geo[j] -> LDS
// Phase 2: h[j][d] = gelu(F1[i,d]-F1[j,d] + geo.W1geo + b1[d]) -> bf16 LDS
// Phase 3: out = h[64x256] @ W2[256x256] + b2 via 16x16x32 bf16 MFMA,
//          with B-fragments software-pipelined (ks=0 issued BEFORE phase 2;
//          ks+1 issued before the MFMAs of ks) — B is W2, independent of h.
// ---------------------------------------------------------------------------
__global__ __launch_bounds__(256) void edge_kernel(
    const float* __restrict__ F1,     // [2048,256]
    const float* __restrict__ pos,    // [32,64,2]
    const float* __restrict__ W1,     // [260,256] (rows 0..3 = geo)
    const float* __restrict__ b1,     // [256]
    const unsigned short* __restrict__ pkW2, // packed bf16 W2
    const float* __restrict__ b2,     // [256]
    float* __restrict__ out)          // [32,64,64,256]
{
    __shared__ unsigned short hsh[64 * HPAD];  // 33792 B
    __shared__ float geo[64][4];               // 1024 B

    int bx  = blockIdx.x;
    int b   = bx >> 6;
    int i   = bx & 63;
    int tid = threadIdx.x;

    int w    = tid >> 6;          // wave id: owns cols [w*64, w*64+64)
    int lane = tid & 63;

    // ---- issue B fragments for ks=0 now: independent of phases 1-2 ----
    const short8* pk = (const short8*)pkW2;
    short8 bcur[4];
    #pragma unroll
    for (int nt = 0; nt < 4; nt++)
        bcur[nt] = pk[(0 * 16 + (w * 4 + nt)) * 64 + lane];

    // ---- phase 1: geometry per j ----
    if (tid < 64) {
        float xi = pos[(b * 64 + i)   * 2 + 0], yi = pos[(b * 64 + i)   * 2 + 1];
        float xj = pos[(b * 64 + tid) * 2 + 0], yj = pos[(b * 64 + tid) * 2 + 1];
        float dx = xi - xj, dy = yi - yj;
        float dist = sqrtf(dx * dx + dy * dy);
        float ang  = atan2f(dy, dx);
        geo[tid][0] = dx; geo[tid][1] = dy; geo[tid][2] = dist; geo[tid][3] = ang;
    }
    __syncthreads();

    // ---- phase 2: h tile (each thread: 4 consecutive d, 16 j values) ----
    {
        int qd = tid & 63;            // d quad index (d0 = qd*4)
        int jg = tid >> 6;            // j residue (j = jj*4 + jg)
        const float4* F1b4 = (const float4*)(F1 + (size_t)b * 64 * 256);
        float4 fi = F1b4[i * 64 + qd];
        float4 w0 = ((const float4*)(W1 + 0 * 256))[qd];
        float4 w1 = ((const float4*)(W1 + 1 * 256))[qd];
        float4 w2 = ((const float4*)(W1 + 2 * 256))[qd];
        float4 w3 = ((const float4*)(W1 + 3 * 256))[qd];
        float4 bb = ((const float4*)b1)[qd];
        float bx0 = fi.x + bb.x, bx1 = fi.y + bb.y;
        float bx2 = fi.z + bb.z, bx3 = fi.w + bb.w;
        int d0 = qd * 4;
        #pragma unroll 4
        for (int jj = 0; jj < 16; jj++) {
            int j = jj * 4 + jg;
            float4 g  = *(const float4*)&geo[j][0];
            float4 fj = F1b4[j * 64 + qd];
            float x0 = fmaf(g.x, w0.x, fmaf(g.y, w1.x, fmaf(g.z, w2.x, fmaf(g.w, w3.x, bx0 - fj.x))));
            float x1 = fmaf(g.x, w0.y, fmaf(g.y, w1.y, fmaf(g.z, w2.y, fmaf(g.w, w3.y, bx1 - fj.y))));
            float x2 = fmaf(g.x, w0.z, fmaf(g.y, w1.z, fmaf(g.z, w2.z, fmaf(g.w, w3.z, bx2 - fj.z))));
            float x3 = fmaf(g.x, w0.w, fmaf(g.y, w1.w, fmaf(g.z, w2.w, fmaf(g.w, w3.w, bx3 - fj.w))));
            float g0 = gelu_erf(x0);
            float g1 = gelu_erf(x1);
            float g2 = gelu_erf(x2);
            float g3 = gelu_erf(x3);
            uint2 pv;
            pv.x = (unsigned int)f2bf(g0) | ((unsigned int)f2bf(g1) << 16);
            pv.y = (unsigned int)f2bf(g2) | ((unsigned int)f2bf(g3) << 16);
            *(uint2*)&hsh[j * HPAD + d0] = pv;   // 8B store, bank-minimal
        }
    }
    __syncthreads();

    // ---- phase 3: GEMM h[64x256] @ W2[256x256], B double-buffered ----
    int q    = lane >> 4;
    int m16  = lane & 15;

    floatx4 acc[4][4];
    #pragma unroll
    for (int a = 0; a < 4; a++)
        #pragma unroll
        for (int c = 0; c < 4; c++) acc[a][c] = (floatx4){0.f, 0.f, 0.f, 0.f};

    #pragma unroll
    for (int ks = 0; ks < 8; ks++) {
        // issue next ks's B fragments first (L2 latency hides under MFMAs)
        short8 bnxt[4];
        if (ks < 7) {
            #pragma unroll
            for (int nt = 0; nt < 4; nt++)
                bnxt[nt] = pk[((ks + 1) * 16 + (w * 4 + nt)) * 64 + lane];
        }
        short8 afr[4];
        #pragma unroll
        for (int mt = 0; mt < 4; mt++) {
            int row = mt * 16 + m16;
            afr[mt] = *(const short8*)&hsh[row * HPAD + ks * 32 + q * 8];
        }
        __builtin_amdgcn_s_setprio(1);
        #pragma unroll
        for (int mt = 0; mt < 4; mt++)
            #pragma unroll
            for (int nt = 0; nt < 4; nt++)
                acc[mt][nt] = __builtin_amdgcn_mfma_f32_16x16x32_bf16(
                    afr[mt], bcur[nt], acc[mt][nt], 0, 0, 0);
        __builtin_amdgcn_s_setprio(0);
        #pragma unroll
        for (int nt = 0; nt < 4; nt++) bcur[nt] = bnxt[nt];
    }

    // ---- epilogue: D[row=(q*4+r)+mt*16][col=m16+nt*16+w*64] + b2 ----
    float* ob = out + (size_t)bx * 64 * 256;
    #pragma unroll
    for (int nt = 0; nt < 4; nt++) {
        int col = w * 64 + nt * 16 + m16;
        float bias = b2[col];
        #pragma unroll
        for (int mt = 0; mt < 4; mt++) {
            int rbase = mt * 16 + q * 4;
            #pragma unroll
            for (int r = 0; r < 4; r++)
                ob[(size_t)(rbase + r) * 256 + col] = acc[mt][nt][r] + bias;
        }
    }
}

extern "C" void kernel_launch(void* const* d_in, const int* in_sizes, int n_in,
                              void* d_out, int out_size, void* d_ws, size_t ws_size,
                              hipStream_t stream) {
    const float* feat = (const float*)d_in[0];  // [32,64,256]
    const float* pos  = (const float*)d_in[1];  // [32,64,2]
    const float* W1   = (const float*)d_in[2];  // [260,256]
    const float* b1   = (const float*)d_in[3];  // [256]
    const float* W2   = (const float*)d_in[4];  // [256,256]
    const float* b2   = (const float*)d_in[5];  // [256]
    float* out = (float*)d_out;

    float* F1 = (float*)d_ws;                          // 2048*256*4 = 2 MiB
    unsigned short* pk = (unsigned short*)((char*)d_ws + 2048 * 256 * 4); // 128 KiB

    prep_kernel<<<288, 256, 0, stream>>>(feat, W1, W2, F1, pk);
    edge_kernel<<<2048, 256, 0, stream>>>(F1, pos, W1, b1, pk, b2, out);
}

// Round 3
// 192.959 us; speedup vs baseline: 1.0735x; 1.0027x over previous
//
#include <hip/hip_runtime.h>
#include <math.h>

typedef __attribute__((ext_vector_type(8))) short short8;
typedef __attribute__((ext_vector_type(4))) float floatx4;

#define HPAD 264  // bf16 elements per LDS h-row: 256 + 8 pad (row stride 528 B, 16B aligned)

__device__ __forceinline__ unsigned short f2bf(float x) {
    union { float f; unsigned int u; } v; v.f = x;
    unsigned int u = v.u;
    return (unsigned short)((u + 0x7fffu + ((u >> 16) & 1u)) >> 16);  // RNE
}

// Exact-GELU via branchless A&S 7.1.26 erf (max |err| 1.5e-7).
__device__ __forceinline__ float gelu_erf(float x) {
    float z  = x * 0.70710678118654752f;
    float az = fabsf(z);
    float t  = __builtin_amdgcn_rcpf(fmaf(0.3275911f, az, 1.0f));
    float p  = fmaf(t, 1.061405429f, -1.453152027f);
    p = fmaf(t, p, 1.421413741f);
    p = fmaf(t, p, -0.284496736f);
    p = fmaf(t, p, 0.254829592f);
    p = p * t;
    float e  = __expf(-z * z);
    float er = fmaf(-p, e, 1.0f);
    er = copysignf(er, z);
    return 0.5f * x * (1.0f + er);
}

// ---------------------------------------------------------------------------
// Prep kernel: blocks [0,256) compute F1 = feat @ W1[4:,:]  (no bias)
//              blocks [256,288) pack W2 into bf16 MFMA B-fragment order.
// ---------------------------------------------------------------------------
__global__ __launch_bounds__(256) void prep_kernel(
    const float* __restrict__ feat,   // [32,64,256]
    const float* __restrict__ W1,     // [260,256]
    const float* __restrict__ W2,     // [256,256]
    float* __restrict__ F1,           // ws: [2048,256]
    unsigned short* __restrict__ pk)  // ws: [65536] bf16
{
    int tid = threadIdx.x;
    if (blockIdx.x < 256) {
        __shared__ float sh[8][256];
        int b  = blockIdx.x >> 3;
        int r0 = (blockIdx.x & 7) * 8;
        const float* fb = feat + (size_t)(b * 64 + r0) * 256;
        #pragma unroll
        for (int r = 0; r < 8; r++) sh[r][tid] = fb[r * 256 + tid];
        __syncthreads();
        float acc[8] = {0.f, 0.f, 0.f, 0.f, 0.f, 0.f, 0.f, 0.f};
        const float* w = W1 + 4 * 256 + tid;
        #pragma unroll 8
        for (int c = 0; c < 256; c++) {
            float wv = w[(size_t)c * 256];
            #pragma unroll
            for (int r = 0; r < 8; r++) acc[r] += sh[r][c] * wv;
        }
        float* o = F1 + (size_t)(b * 64 + r0) * 256 + tid;
        #pragma unroll
        for (int r = 0; r < 8; r++) o[r * 256] = acc[r];
    } else {
        int g = (blockIdx.x - 256) * 256 + tid;   // 0..8191
        int kt   = g >> 10;
        int rem  = g & 1023;
        int nt   = rem >> 6;
        int lane = rem & 63;
        int n  = nt * 16 + (lane & 15);
        int kb = kt * 32 + (lane >> 4) * 8;
        short8 v;
        #pragma unroll
        for (int e = 0; e < 8; e++) v[e] = (short)f2bf(W2[(size_t)(kb + e) * 256 + n]);
        ((short8*)pk)[g] = v;
    }
}

// ---------------------------------------------------------------------------
// Main kernel: one block per (b, i). 256 threads = 4 waves.
// __launch_bounds__(256,4): pin VGPR<=128 so 4 blocks/CU (LDS allows 4) —
// 4 waves/SIMD TLP across all phases.
// Phase 1: geo[j] -> LDS
// Phase 2: h[j][d] = gelu(F1[i,d]-F1[j,d] + geo.W1geo + b1[d]) -> bf16 LDS
// Phase 3: out = h[64x256] @ W2 + b2; bias folded into acc init, B fragments
//          software-pipelined one ks ahead; nontemporal output stores.
// ---------------------------------------------------------------------------
__global__ __launch_bounds__(256, 4) void edge_kernel(
    const float* __restrict__ F1,     // [2048,256]
    const float* __restrict__ pos,    // [32,64,2]
    const float* __restrict__ W1,     // [260,256] (rows 0..3 = geo)
    const float* __restrict__ b1,     // [256]
    const unsigned short* __restrict__ pkW2, // packed bf16 W2
    const float* __restrict__ b2,     // [256]
    float* __restrict__ out)          // [32,64,64,256]
{
    __shared__ unsigned short hsh[64 * HPAD];  // 33792 B
    __shared__ float geo[64][4];               // 1024 B

    int bx  = blockIdx.x;
    int b   = bx >> 6;
    int i   = bx & 63;
    int tid = threadIdx.x;

    int w    = tid >> 6;          // wave id: owns cols [w*64, w*64+64)
    int lane = tid & 63;
    int q    = lane >> 4;
    int m16  = lane & 15;

    // ---- issue B fragments for ks=0 now: independent of phases 1-2 ----
    const short8* pk = (const short8*)pkW2;
    short8 bcur[4];
    #pragma unroll
    for (int nt = 0; nt < 4; nt++)
        bcur[nt] = pk[(0 * 16 + (w * 4 + nt)) * 64 + lane];

    // bias per owned column (col = w*64 + nt*16 + m16); folded into acc init
    float bias[4];
    #pragma unroll
    for (int nt = 0; nt < 4; nt++) bias[nt] = b2[w * 64 + nt * 16 + m16];

    // ---- phase 1: geometry per j ----
    if (tid < 64) {
        float xi = pos[(b * 64 + i)   * 2 + 0], yi = pos[(b * 64 + i)   * 2 + 1];
        float xj = pos[(b * 64 + tid) * 2 + 0], yj = pos[(b * 64 + tid) * 2 + 1];
        float dx = xi - xj, dy = yi - yj;
        float dist = sqrtf(dx * dx + dy * dy);
        float ang  = atan2f(dy, dx);
        geo[tid][0] = dx; geo[tid][1] = dy; geo[tid][2] = dist; geo[tid][3] = ang;
    }
    __syncthreads();

    // ---- phase 2: h tile (each thread: 4 consecutive d, 16 j values) ----
    {
        int qd = tid & 63;            // d quad index (d0 = qd*4)
        int jg = tid >> 6;            // j residue (j = jj*4 + jg)
        const float4* F1b4 = (const float4*)(F1 + (size_t)b * 64 * 256);
        float4 fi = F1b4[i * 64 + qd];
        float4 w0 = ((const float4*)(W1 + 0 * 256))[qd];
        float4 w1 = ((const float4*)(W1 + 1 * 256))[qd];
        float4 w2 = ((const float4*)(W1 + 2 * 256))[qd];
        float4 w3 = ((const float4*)(W1 + 3 * 256))[qd];
        float4 bb = ((const float4*)b1)[qd];
        float bx0 = fi.x + bb.x, bx1 = fi.y + bb.y;
        float bx2 = fi.z + bb.z, bx3 = fi.w + bb.w;
        int d0 = qd * 4;
        #pragma unroll 4
        for (int jj = 0; jj < 16; jj++) {
            int j = jj * 4 + jg;
            float4 g  = *(const float4*)&geo[j][0];
            float4 fj = F1b4[j * 64 + qd];
            float x0 = fmaf(g.x, w0.x, fmaf(g.y, w1.x, fmaf(g.z, w2.x, fmaf(g.w, w3.x, bx0 - fj.x))));
            float x1 = fmaf(g.x, w0.y, fmaf(g.y, w1.y, fmaf(g.z, w2.y, fmaf(g.w, w3.y, bx1 - fj.y))));
            float x2 = fmaf(g.x, w0.z, fmaf(g.y, w1.z, fmaf(g.z, w2.z, fmaf(g.w, w3.z, bx2 - fj.z))));
            float x3 = fmaf(g.x, w0.w, fmaf(g.y, w1.w, fmaf(g.z, w2.w, fmaf(g.w, w3.w, bx3 - fj.w))));
            float g0 = gelu_erf(x0);
            float g1 = gelu_erf(x1);
            float g2 = gelu_erf(x2);
            float g3 = gelu_erf(x3);
            uint2 pv;
            pv.x = (unsigned int)f2bf(g0) | ((unsigned int)f2bf(g1) << 16);
            pv.y = (unsigned int)f2bf(g2) | ((unsigned int)f2bf(g3) << 16);
            *(uint2*)&hsh[j * HPAD + d0] = pv;   // 8B store, bank-minimal
        }
    }
    __syncthreads();

    // ---- phase 3: GEMM h[64x256] @ W2[256x256], B double-buffered ----
    floatx4 acc[4][4];
    #pragma unroll
    for (int mt = 0; mt < 4; mt++)
        #pragma unroll
        for (int nt = 0; nt < 4; nt++)
            acc[mt][nt] = (floatx4){bias[nt], bias[nt], bias[nt], bias[nt]};

    #pragma unroll
    for (int ks = 0; ks < 8; ks++) {
        // issue next ks's B fragments first (L2 latency hides under MFMAs)
        short8 bnxt[4];
        if (ks < 7) {
            #pragma unroll
            for (int nt = 0; nt < 4; nt++)
                bnxt[nt] = pk[((ks + 1) * 16 + (w * 4 + nt)) * 64 + lane];
        }
        short8 afr[4];
        #pragma unroll
        for (int mt = 0; mt < 4; mt++) {
            int row = mt * 16 + m16;
            afr[mt] = *(const short8*)&hsh[row * HPAD + ks * 32 + q * 8];
        }
        __builtin_amdgcn_s_setprio(1);
        #pragma unroll
        for (int mt = 0; mt < 4; mt++)
            #pragma unroll
            for (int nt = 0; nt < 4; nt++)
                acc[mt][nt] = __builtin_amdgcn_mfma_f32_16x16x32_bf16(
                    afr[mt], bcur[nt], acc[mt][nt], 0, 0, 0);
        __builtin_amdgcn_s_setprio(0);
        #pragma unroll
        for (int nt = 0; nt < 4; nt++) bcur[nt] = bnxt[nt];
    }

    // ---- epilogue: pure nontemporal stores (bias already in acc) ----
    // D[row=(q*4+r)+mt*16][col=m16+nt*16+w*64]
    float* ob = out + (size_t)bx * 64 * 256;
    #pragma unroll
    for (int nt = 0; nt < 4; nt++) {
        int col = w * 64 + nt * 16 + m16;
        #pragma unroll
        for (int mt = 0; mt < 4; mt++) {
            int rbase = mt * 16 + q * 4;
            #pragma unroll
            for (int r = 0; r < 4; r++)
                __builtin_nontemporal_store(acc[mt][nt][r],
                    &ob[(size_t)(rbase + r) * 256 + col]);
        }
    }
}

extern "C" void kernel_launch(void* const* d_in, const int* in_sizes, int n_in,
                              void* d_out, int out_size, void* d_ws, size_t ws_size,
                              hipStream_t stream) {
    const float* feat = (const float*)d_in[0];  // [32,64,256]
    const float* pos  = (const float*)d_in[1];  // [32,64,2]
    const float* W1   = (const float*)d_in[2];  // [260,256]
    const float* b1   = (const float*)d_in[3];  // [256]
    const float* W2   = (const float*)d_in[4];  // [256,256]
    const float* b2   = (const float*)d_in[5];  // [256]
    float* out = (float*)d_out;

    float* F1 = (float*)d_ws;                          // 2048*256*4 = 2 MiB
    unsigned short* pk = (unsigned short*)((char*)d_ws + 2048 * 256 * 4); // 128 KiB

    prep_kernel<<<288, 256, 0, stream>>>(feat, W1, W2, F1, pk);
    edge_kernel<<<2048, 256, 0, stream>>>(F1, pos, W1, b1, pk, b2, out);
}